// Round 1
// baseline (335.612 us; speedup 1.0000x reference)
//
#include <hip/hip_runtime.h>
#include <hip/hip_bf16.h>

#define B_  2
#define S_  2048
#define H_  1024
#define NH_ 16
#define HD_ 64

typedef unsigned short u16;
typedef __attribute__((ext_vector_type(4))) float  f32x4;
typedef __attribute__((ext_vector_type(8))) __bf16 bf16x8;
typedef __attribute__((ext_vector_type(8))) unsigned short u16x8;
typedef __attribute__((ext_vector_type(4))) unsigned short u16x4;

// f32 -> bf16, round-to-nearest-even
__device__ __forceinline__ u16 f2bf(float f) {
  unsigned u = __builtin_bit_cast(unsigned, f);
  u += 0x7fffu + ((u >> 16) & 1u);
  return (u16)(u >> 16);
}

// async global->LDS, 16B per lane; LDS dest = wave-uniform base + lane*16
__device__ __forceinline__ void gload_lds16(const void* g, void* l) {
  __builtin_amdgcn_global_load_lds(
      (const __attribute__((address_space(1))) void*)g,
      (__attribute__((address_space(3))) void*)l, 16, 0, 0);
}

__global__ __launch_bounds__(256) void cvt_bf16(const float* __restrict__ in,
                                                u16* __restrict__ out, int n) {
  int i = (blockIdx.x * blockDim.x + threadIdx.x) * 4;
  if (i >= n) return;
  float4 v = *reinterpret_cast<const float4*>(in + i);
  u16x4 o;
  o[0] = f2bf(v.x); o[1] = f2bf(v.y); o[2] = f2bf(v.z); o[3] = f2bf(v.w);
  *reinterpret_cast<u16x4*>(out + i) = o;
}

__device__ __forceinline__ void store_out(float* C, size_t idx, float v) { C[idx] = v; }
__device__ __forceinline__ void store_out(u16* C, size_t idx, float v) { C[idx] = f2bf(v); }

// C[m,n] = (sum_k A[m,k] * Bw[n,k] + bias[n]) * oscale
// A: M x K bf16 row-major, Bw: N x K bf16 row-major (i.e. W for y = x W^T).
// 128x128 tile, BK=32, 4 waves (2x2), 16x16x32 MFMA. m97-structure.
template <typename OutT>
__global__ __launch_bounds__(256) void gemm_bt(const u16* __restrict__ A,
                                               const u16* __restrict__ Bw,
                                               const float* __restrict__ bias,
                                               OutT* __restrict__ C,
                                               int M, int N, int K, float oscale) {
  __shared__ u16 lsA[128 * 32];
  __shared__ u16 lsB[128 * 32];
  const int t = threadIdx.x;
  const int w = t >> 6, lane = t & 63;
  const int g = lane >> 4, c = lane & 15;
  const int m0 = blockIdx.x * 128, n0 = blockIdx.y * 128;
  const int wr = w >> 1, wc = w & 1;

  f32x4 acc[4][4] = {};

  const int rowS = w * 16 + (lane >> 2);   // staging row within 64-row round
  const int colS = (lane & 3) * 8;         // staging col (elements)

  for (int k0 = 0; k0 < K; k0 += 32) {
    __syncthreads();
#pragma unroll
    for (int r = 0; r < 2; ++r) {
      int row = r * 64 + rowS;
      gload_lds16(A  + (size_t)(m0 + row) * K + k0 + colS, &lsA[r * 2048 + w * 512]);
      gload_lds16(Bw + (size_t)(n0 + row) * K + k0 + colS, &lsB[r * 2048 + w * 512]);
    }
    asm volatile("s_waitcnt vmcnt(0)" ::: "memory");
    __syncthreads();

    bf16x8 af[4], bfr[4];
#pragma unroll
    for (int mi = 0; mi < 4; ++mi) {
      int row = wr * 64 + mi * 16 + c;
      af[mi] = *reinterpret_cast<const bf16x8*>(&lsA[row * 32 + g * 8]);
    }
#pragma unroll
    for (int ni = 0; ni < 4; ++ni) {
      int row = wc * 64 + ni * 16 + c;
      bfr[ni] = *reinterpret_cast<const bf16x8*>(&lsB[row * 32 + g * 8]);
    }
#pragma unroll
    for (int mi = 0; mi < 4; ++mi)
#pragma unroll
      for (int ni = 0; ni < 4; ++ni)
        acc[mi][ni] = __builtin_amdgcn_mfma_f32_16x16x32_bf16(af[mi], bfr[ni], acc[mi][ni], 0, 0, 0);
  }

  // epilogue: C/D layout col = lane&15, row = (lane>>4)*4 + r   [m89-verified]
#pragma unroll
  for (int mi = 0; mi < 4; ++mi) {
    int rowb = m0 + wr * 64 + mi * 16 + g * 4;
#pragma unroll
    for (int ni = 0; ni < 4; ++ni) {
      int col = n0 + wc * 64 + ni * 16 + c;
      float bv = bias[col];
#pragma unroll
      for (int r = 0; r < 4; ++r) {
        float v = (acc[mi][ni][r] + bv) * oscale;
        store_out(C, (size_t)(rowb + r) * N + col, v);
      }
    }
  }
}

// Flash attention, causal. Grid: (S/64, NH, B). 4 waves, each owns 16 q-rows.
// Q,K,V,O: [B,S,H] bf16 with head h at columns [h*64, h*64+64). Q pre-scaled by 1/8.
__global__ __launch_bounds__(256) void attn_fwd(const u16* __restrict__ Qg,
                                                const u16* __restrict__ Kg,
                                                const u16* __restrict__ Vg,
                                                u16* __restrict__ Og) {
  __shared__ u16 lsK[32 * 64];       // [kv][d], rows of 128B, XOR-swizzled content
  __shared__ u16 lsVt[64][40];       // [d][kv], +8 pad
  __shared__ u16 lsP[4][16 * 40];    // per-wave P tile [16 q][32 kv], +8 pad

  const int qt = blockIdx.x, h = blockIdx.y, b = blockIdx.z;
  const int t = threadIdx.x, w = t >> 6, lane = t & 63;
  const int g = lane >> 4, c = lane & 15;
  const size_t headoff = (size_t)b * S_ * H_ + (size_t)h * HD_;
  const int q0 = qt * 64 + w * 16;

  // Q fragments held in registers for the whole kernel (A-frag: row=lane&15, k=8g..)
  bf16x8 aq[2];
#pragma unroll
  for (int kh = 0; kh < 2; ++kh)
    aq[kh] = *reinterpret_cast<const bf16x8*>(Qg + headoff + (size_t)(q0 + c) * H_ + kh * 32 + g * 8);

  f32x4 oacc[4] = {};
  float mrow[4], lrow[4];
#pragma unroll
  for (int r = 0; r < 4; ++r) { mrow[r] = -1e30f; lrow[r] = 0.f; }

  // K staging: linear LDS dest, inverse-swizzled global source (rule 21)
  const int kO     = w * 1024 + lane * 16;      // byte offset in lsK
  const int kRow   = kO >> 7;                   // kv row 0..31
  const int kSrcCb = (kO & 127) ^ ((kRow & 7) << 4);
  // V staging: each thread loads 8 elems of one kv row, scatters transposed
  const int vRow = t >> 3;                      // kv row 0..31
  const int vC8  = (t & 7) * 8;                 // d start

  const int kv_end = qt * 64 + 64;
  for (int kv0 = 0; kv0 < kv_end; kv0 += 32) {
    __syncthreads();
    gload_lds16((const char*)(Kg + headoff + (size_t)(kv0 + kRow) * H_) + kSrcCb,
                (char*)lsK + w * 1024);
    u16x8 vv = *reinterpret_cast<const u16x8*>(Vg + headoff + (size_t)(kv0 + vRow) * H_ + vC8);
#pragma unroll
    for (int j = 0; j < 8; ++j) lsVt[vC8 + j][vRow] = vv[j];
    asm volatile("s_waitcnt vmcnt(0)" ::: "memory");
    __syncthreads();

    // QK^T: two 16x16 score tiles (kv cols 0-15, 16-31)
    f32x4 sc[2];
#pragma unroll
    for (int nj = 0; nj < 2; ++nj) {
      int krow = nj * 16 + c;
      int sw = (krow & 7) << 4;
      const char* base = (const char*)lsK + krow * 128;
      bf16x8 bk0 = *reinterpret_cast<const bf16x8*>(base + ((g * 16) ^ sw));
      bf16x8 bk1 = *reinterpret_cast<const bf16x8*>(base + ((64 + g * 16) ^ sw));
      f32x4 z = {};
      z = __builtin_amdgcn_mfma_f32_16x16x32_bf16(aq[0], bk0, z, 0, 0, 0);
      z = __builtin_amdgcn_mfma_f32_16x16x32_bf16(aq[1], bk1, z, 0, 0, 0);
      sc[nj] = z;
    }

    // causal mask + online softmax (C layout: row = 4g+r, col = c)
    float p[2][4];
#pragma unroll
    for (int r = 0; r < 4; ++r) {
      int qrow = q0 + 4 * g + r;
#pragma unroll
      for (int nj = 0; nj < 2; ++nj) {
        int kcol = kv0 + nj * 16 + c;
        if (kcol > qrow) sc[nj][r] = -1e30f;
      }
      float lm = fmaxf(sc[0][r], sc[1][r]);
#pragma unroll
      for (int off = 1; off < 16; off <<= 1) lm = fmaxf(lm, __shfl_xor(lm, off));
      float mnew = fmaxf(mrow[r], lm);
      float p0 = __expf(sc[0][r] - mnew);
      float p1 = __expf(sc[1][r] - mnew);
      p[0][r] = p0; p[1][r] = p1;
      float rs = p0 + p1;
#pragma unroll
      for (int off = 1; off < 16; off <<= 1) rs += __shfl_xor(rs, off);
      float scale = __expf(mrow[r] - mnew);
      lrow[r] = lrow[r] * scale + rs;
      mrow[r] = mnew;
#pragma unroll
      for (int dt = 0; dt < 4; ++dt) oacc[dt][r] = oacc[dt][r] * scale;
    }

    // P (C-layout) -> LDS -> A-frag layout
#pragma unroll
    for (int r = 0; r < 4; ++r)
#pragma unroll
      for (int nj = 0; nj < 2; ++nj)
        lsP[w][(4 * g + r) * 40 + nj * 16 + c] = f2bf(p[nj][r]);
    __syncthreads();

    bf16x8 pa = *reinterpret_cast<const bf16x8*>(&lsP[w][c * 40 + g * 8]);
#pragma unroll
    for (int dt = 0; dt < 4; ++dt) {
      bf16x8 bv = *reinterpret_cast<const bf16x8*>(&lsVt[dt * 16 + c][g * 8]);
      oacc[dt] = __builtin_amdgcn_mfma_f32_16x16x32_bf16(pa, bv, oacc[dt], 0, 0, 0);
    }
  }

  // epilogue: O = acc / l
#pragma unroll
  for (int r = 0; r < 4; ++r) {
    float inv = 1.f / lrow[r];
    int qrow = q0 + 4 * g + r;
#pragma unroll
    for (int dt = 0; dt < 4; ++dt)
      Og[headoff + (size_t)qrow * H_ + dt * 16 + c] = f2bf(oacc[dt][r] * inv);
  }
}

extern "C" void kernel_launch(void* const* d_in, const int* in_sizes, int n_in,
                              void* d_out, int out_size, void* d_ws, size_t ws_size,
                              hipStream_t stream) {
  const float* x  = (const float*)d_in[0];
  const float* Wq = (const float*)d_in[1];
  const float* bq = (const float*)d_in[2];
  const float* Wk = (const float*)d_in[3];
  const float* bk = (const float*)d_in[4];
  const float* Wv = (const float*)d_in[5];
  const float* bv = (const float*)d_in[6];
  const float* Wo = (const float*)d_in[7];
  const float* bo = (const float*)d_in[8];
  float* out = (float*)d_out;

  const size_t MT = (size_t)B_ * S_;            // 4096
  char* p = (char*)d_ws;
  u16* xb  = (u16*)p; p += MT * H_ * 2;         // also reused as ctx buffer
  u16* Wqb = (u16*)p; p += (size_t)H_ * H_ * 2;
  u16* Wkb = (u16*)p; p += (size_t)H_ * H_ * 2;
  u16* Wvb = (u16*)p; p += (size_t)H_ * H_ * 2;
  u16* Wob = (u16*)p; p += (size_t)H_ * H_ * 2;
  u16* Qb  = (u16*)p; p += MT * H_ * 2;
  u16* Kb  = (u16*)p; p += MT * H_ * 2;
  u16* Vb  = (u16*)p; p += MT * H_ * 2;
  u16* Cb  = xb;                                 // x dead after QKV GEMMs

  cvt_bf16<<<(int)(MT * H_ / 1024), 256, 0, stream>>>(x,  xb,  (int)(MT * H_));
  cvt_bf16<<<H_ * H_ / 1024, 256, 0, stream>>>(Wq, Wqb, H_ * H_);
  cvt_bf16<<<H_ * H_ / 1024, 256, 0, stream>>>(Wk, Wkb, H_ * H_);
  cvt_bf16<<<H_ * H_ / 1024, 256, 0, stream>>>(Wv, Wvb, H_ * H_);
  cvt_bf16<<<H_ * H_ / 1024, 256, 0, stream>>>(Wo, Wob, H_ * H_);

  dim3 gg(MT / 128, H_ / 128);   // (32, 8)
  gemm_bt<u16><<<gg, 256, 0, stream>>>(xb, Wqb, bq, Qb, (int)MT, H_, H_, 0.125f); // 1/sqrt(64) folded
  gemm_bt<u16><<<gg, 256, 0, stream>>>(xb, Wkb, bk, Kb, (int)MT, H_, H_, 1.0f);
  gemm_bt<u16><<<gg, 256, 0, stream>>>(xb, Wvb, bv, Vb, (int)MT, H_, H_, 1.0f);

  attn_fwd<<<dim3(S_ / 64, NH_, B_), 256, 0, stream>>>(Qb, Kb, Vb, Cb);

  gemm_bt<float><<<gg, 256, 0, stream>>>(Cb, Wob, bo, out, (int)MT, H_, H_, 1.0f);
}

// Round 2
// 187.465 us; speedup vs baseline: 1.7903x; 1.7903x over previous
//
#include <hip/hip_runtime.h>
#include <hip/hip_bf16.h>

#define B_  2
#define S_  2048
#define H_  1024
#define NH_ 16
#define HD_ 64

typedef unsigned short u16;
typedef __attribute__((ext_vector_type(4))) float  f32x4;
typedef __attribute__((ext_vector_type(8))) __bf16 bf16x8;
typedef __attribute__((ext_vector_type(8))) unsigned short u16x8;
typedef __attribute__((ext_vector_type(4))) unsigned short u16x4;

// f32 -> bf16, round-to-nearest-even
__device__ __forceinline__ u16 f2bf(float f) {
  unsigned u = __builtin_bit_cast(unsigned, f);
  u += 0x7fffu + ((u >> 16) & 1u);
  return (u16)(u >> 16);
}

// async global->LDS, 16B per lane; LDS dest = wave-uniform base + lane*16
__device__ __forceinline__ void gload_lds16(const void* g, void* l) {
  __builtin_amdgcn_global_load_lds(
      (const __attribute__((address_space(1))) void*)g,
      (__attribute__((address_space(3))) void*)l, 16, 0, 0);
}

__global__ __launch_bounds__(256) void cvt_bf16(const float* __restrict__ in,
                                                u16* __restrict__ out, int n) {
  int i = (blockIdx.x * blockDim.x + threadIdx.x) * 4;
  if (i >= n) return;
  float4 v = *reinterpret_cast<const float4*>(in + i);
  u16x4 o;
  o[0] = f2bf(v.x); o[1] = f2bf(v.y); o[2] = f2bf(v.z); o[3] = f2bf(v.w);
  *reinterpret_cast<u16x4*>(out + i) = o;
}

__device__ __forceinline__ void store_out(float* C, size_t idx, float v) { C[idx] = v; }
__device__ __forceinline__ void store_out(u16* C, size_t idx, float v) { C[idx] = f2bf(v); }

// ---------------- GEMM core: C[m,n] = (sum_k A[m,k]*Bw[n,k] + bias[n]) * oscale
// A: MxK bf16 row-major; Bw: NxK bf16 row-major (y = x W^T form).
// Block tile: (MI*32) x 128, BK=32, 4 waves (2x2), 16x16x32 MFMA.
template <int MI, typename OutT>
__device__ __forceinline__ void gemm_core(const u16* __restrict__ A, const u16* __restrict__ Bw,
                                          const float* __restrict__ bias, OutT* __restrict__ C,
                                          int M, int N, int K, float oscale, int m0, int n0,
                                          u16* lsA, u16* lsB) {
  const int t = threadIdx.x;
  const int w = t >> 6, lane = t & 63;
  const int g = lane >> 4, c = lane & 15;
  const int wr = w >> 1, wc = w & 1;

  f32x4 acc[MI][4] = {};
  const int rowS = w * 16 + (lane >> 2);   // staging row within 64-row round
  const int colS = (lane & 3) * 8;         // staging col (elements)

  for (int k0 = 0; k0 < K; k0 += 32) {
    __syncthreads();
#pragma unroll
    for (int r = 0; r < MI / 2; ++r)
      gload_lds16(A + (size_t)(m0 + r * 64 + rowS) * K + k0 + colS, lsA + r * 2048 + w * 512);
#pragma unroll
    for (int r = 0; r < 2; ++r)
      gload_lds16(Bw + (size_t)(n0 + r * 64 + rowS) * K + k0 + colS, lsB + r * 2048 + w * 512);
    asm volatile("s_waitcnt vmcnt(0)" ::: "memory");
    __syncthreads();

    bf16x8 af[MI], bfr[4];
#pragma unroll
    for (int mi = 0; mi < MI; ++mi)
      af[mi] = *reinterpret_cast<const bf16x8*>(&lsA[(wr * (MI * 16) + mi * 16 + c) * 32 + g * 8]);
#pragma unroll
    for (int ni = 0; ni < 4; ++ni)
      bfr[ni] = *reinterpret_cast<const bf16x8*>(&lsB[(wc * 64 + ni * 16 + c) * 32 + g * 8]);
#pragma unroll
    for (int mi = 0; mi < MI; ++mi)
#pragma unroll
      for (int ni = 0; ni < 4; ++ni)
        acc[mi][ni] = __builtin_amdgcn_mfma_f32_16x16x32_bf16(af[mi], bfr[ni], acc[mi][ni], 0, 0, 0);
  }

  // epilogue: C/D layout col = lane&15, row = (lane>>4)*4 + r   [m89-verified]
#pragma unroll
  for (int mi = 0; mi < MI; ++mi) {
    int rowb = m0 + wr * (MI * 16) + mi * 16 + g * 4;
#pragma unroll
    for (int ni = 0; ni < 4; ++ni) {
      int col = n0 + wc * 64 + ni * 16 + c;
      float bv = bias[col];
#pragma unroll
      for (int r = 0; r < 4; ++r) {
        float v = (acc[mi][ni][r] + bv) * oscale;
        store_out(C, (size_t)(rowb + r) * N + col, v);
      }
    }
  }
}

template <int MI, typename OutT>
__global__ __launch_bounds__(256) void gemm_bt(const u16* __restrict__ A, const u16* __restrict__ Bw,
                                               const float* __restrict__ bias, OutT* __restrict__ C,
                                               int M, int N, int K, float oscale) {
  __shared__ u16 lsA[MI * 1024];
  __shared__ u16 lsB[4096];
  gemm_core<MI, OutT>(A, Bw, bias, C, M, N, K, oscale,
                      blockIdx.x * (MI * 32), blockIdx.y * 128, lsA, lsB);
}

// Fused QKV projection: grid (M/128, 3072/128). Output column group selects Q/K/V.
__global__ __launch_bounds__(256) void gemm_qkv(const u16* __restrict__ xb,
                                                const u16* __restrict__ Wq, const u16* __restrict__ Wk,
                                                const u16* __restrict__ Wv,
                                                const float* __restrict__ bq, const float* __restrict__ bk,
                                                const float* __restrict__ bv,
                                                u16* __restrict__ Q, u16* __restrict__ Kb, u16* __restrict__ Vb,
                                                int M, int K, float qscale) {
  __shared__ u16 lsA[4096];
  __shared__ u16 lsB[4096];
  const int m0 = blockIdx.x * 128;
  const int ng = blockIdx.y * 128;
  const int sel = ng >> 10, n0 = ng & 1023;
  const u16*  W    = sel == 0 ? Wq : sel == 1 ? Wk : Wv;
  const float* bia = sel == 0 ? bq : sel == 1 ? bk : bv;
  u16*        Cp   = sel == 0 ? Q  : sel == 1 ? Kb : Vb;
  float os = sel == 0 ? qscale : 1.0f;
  gemm_core<4, u16>(xb, W, bia, Cp, M, 1024, K, os, m0, n0, lsA, lsB);
}

// ---------------- Flash attention, causal. 1D grid of 1024 blocks (XCD-swizzled).
// 4 waves/block, each owns 16 q-rows; KVBLK=64, K=64(head dim) per MFMA chain.
// Q was pre-scaled by log2(e)/8 -> softmax in exp2 domain.
__global__ __launch_bounds__(256) void attn_fwd(const u16* __restrict__ Qg,
                                                const u16* __restrict__ Kg,
                                                const u16* __restrict__ Vg,
                                                u16* __restrict__ Og) {
  __shared__ u16 lsK[64 * 64];        // [kv][d], 128B rows, XOR-swizzled content
  __shared__ u16 lsVt[64 * 72];       // [d][kv^8s] with s=(d>>3)&7, stride 72
  __shared__ u16 lsP[4][16 * 72];     // per-wave P tile [16 q][64 kv], stride 72

  // XCD swizzle: 8 XCDs x 128 contiguous wgs -> whole heads per XCD (K/V L2-resident)
  const int blk = blockIdx.x;
  const int wg  = (blk & 7) * 128 + (blk >> 3);
  const int qt = wg & 31, h = (wg >> 5) & 15, b = wg >> 9;

  const int t = threadIdx.x, w = t >> 6, lane = t & 63;
  const int g = lane >> 4, c = lane & 15;
  const size_t headoff = (size_t)b * S_ * H_ + (size_t)h * HD_;
  const int q0 = qt * 64 + w * 16;

  // Q fragments in registers (A-frag: row=lane&15, k=8g.. within 32-chunk)
  bf16x8 aq[2];
#pragma unroll
  for (int kh = 0; kh < 2; ++kh)
    aq[kh] = *reinterpret_cast<const bf16x8*>(Qg + headoff + (size_t)(q0 + c) * H_ + kh * 32 + g * 8);

  f32x4 oacc[4] = {};
  float mrow[4], lrow[4];
#pragma unroll
  for (int r = 0; r < 4; ++r) { mrow[r] = -1e30f; lrow[r] = 0.f; }

  // K staging: linear LDS dest, inverse-swizzled global source (rule 21).
  // round r covers kv rows 32r..32r+31; (row+32)&7 == row&7 so col is round-invariant.
  const int kRow0 = (w * 1024 + lane * 16) >> 7;                    // 0..31
  const int kColB = ((w * 1024 + lane * 16) & 127) ^ ((kRow0 & 7) << 4);
  // V staging: thread -> (kv = t>>3 (+32r), d0 = (t&7)*8); write col = kv ^ 8*(t&7)
  const int vKv = t >> 3, vD0 = (t & 7) * 8, vS = t & 7;

  const int kv_last = qt * 64;
  for (int kv0 = 0; kv0 <= kv_last; kv0 += 64) {
    __syncthreads();   // all waves done reading previous K/V tile
#pragma unroll
    for (int r = 0; r < 2; ++r)
      gload_lds16((const char*)(Kg + headoff + (size_t)(kv0 + 32 * r + kRow0) * H_) + kColB,
                  (char*)lsK + r * 4096 + w * 1024);
#pragma unroll
    for (int r = 0; r < 2; ++r) {
      int kv = vKv + 32 * r;
      u16x8 vv = *reinterpret_cast<const u16x8*>(Vg + headoff + (size_t)(kv0 + kv) * H_ + vD0);
      int kvx = kv ^ (8 * vS);
#pragma unroll
      for (int j = 0; j < 8; ++j) lsVt[(vD0 + j) * 72 + kvx] = vv[j];
    }
    asm volatile("s_waitcnt vmcnt(0)" ::: "memory");
    __syncthreads();

    // QK^T: four 16x16 score tiles over kv columns
    f32x4 sc[4];
#pragma unroll
    for (int nj = 0; nj < 4; ++nj) {
      int krow = nj * 16 + c;
      int sw = (krow & 7) << 4;
      const char* base = (const char*)lsK + krow * 128;
      bf16x8 bk0 = *reinterpret_cast<const bf16x8*>(base + ((g * 16) ^ sw));
      bf16x8 bk1 = *reinterpret_cast<const bf16x8*>(base + ((64 + g * 16) ^ sw));
      f32x4 z = {};
      z = __builtin_amdgcn_mfma_f32_16x16x32_bf16(aq[0], bk0, z, 0, 0, 0);
      z = __builtin_amdgcn_mfma_f32_16x16x32_bf16(aq[1], bk1, z, 0, 0, 0);
      sc[nj] = z;
    }

    // causal mask (diag tile only) + online softmax (exp2 domain).
    // C layout: row = 4g+r, col = c.
    const bool diag = (kv0 + 63 > q0);
    float p[4][4];
#pragma unroll
    for (int r = 0; r < 4; ++r) {
      int qrow = q0 + 4 * g + r;
      if (diag) {
#pragma unroll
        for (int nj = 0; nj < 4; ++nj)
          if (kv0 + nj * 16 + c > qrow) sc[nj][r] = -1e30f;
      }
      float lm = fmaxf(fmaxf(sc[0][r], sc[1][r]), fmaxf(sc[2][r], sc[3][r]));
#pragma unroll
      for (int off = 1; off < 16; off <<= 1) lm = fmaxf(lm, __shfl_xor(lm, off));
      float mnew = fmaxf(mrow[r], lm);
      float rs = 0.f;
#pragma unroll
      for (int nj = 0; nj < 4; ++nj) {
        p[nj][r] = exp2f(sc[nj][r] - mnew);
        rs += p[nj][r];
      }
#pragma unroll
      for (int off = 1; off < 16; off <<= 1) rs += __shfl_xor(rs, off);
      float scale = exp2f(mrow[r] - mnew);
      lrow[r] = lrow[r] * scale + rs;
      mrow[r] = mnew;
#pragma unroll
      for (int dt = 0; dt < 4; ++dt) oacc[dt][r] *= scale;
    }

    // P (C-layout) -> per-wave LDS -> A-frag layout. Wave-local: fence, no barrier.
#pragma unroll
    for (int r = 0; r < 4; ++r)
#pragma unroll
      for (int nj = 0; nj < 4; ++nj)
        lsP[w][(4 * g + r) * 72 + nj * 16 + c] = f2bf(p[nj][r]);
    asm volatile("s_waitcnt lgkmcnt(0)" ::: "memory");
    __builtin_amdgcn_sched_barrier(0);

    bf16x8 pa0 = *reinterpret_cast<const bf16x8*>(&lsP[w][c * 72 + g * 8]);
    bf16x8 pa1 = *reinterpret_cast<const bf16x8*>(&lsP[w][c * 72 + 32 + g * 8]);
#pragma unroll
    for (int dt = 0; dt < 4; ++dt) {
      int d = dt * 16 + c;
      int sx = ((d >> 3) & 7) << 4;   // byte xor
      const char* vb = (const char*)lsVt + d * 144;
      bf16x8 bv0 = *reinterpret_cast<const bf16x8*>(vb + ((g * 16) ^ sx));
      bf16x8 bv1 = *reinterpret_cast<const bf16x8*>(vb + ((64 + g * 16) ^ sx));
      oacc[dt] = __builtin_amdgcn_mfma_f32_16x16x32_bf16(pa0, bv0, oacc[dt], 0, 0, 0);
      oacc[dt] = __builtin_amdgcn_mfma_f32_16x16x32_bf16(pa1, bv1, oacc[dt], 0, 0, 0);
    }
  }

  // epilogue: O = acc / l
#pragma unroll
  for (int r = 0; r < 4; ++r) {
    float inv = 1.f / lrow[r];
    int qrow = q0 + 4 * g + r;
#pragma unroll
    for (int dt = 0; dt < 4; ++dt)
      Og[headoff + (size_t)qrow * H_ + dt * 16 + c] = f2bf(oacc[dt][r] * inv);
  }
}

extern "C" void kernel_launch(void* const* d_in, const int* in_sizes, int n_in,
                              void* d_out, int out_size, void* d_ws, size_t ws_size,
                              hipStream_t stream) {
  const float* x  = (const float*)d_in[0];
  const float* Wq = (const float*)d_in[1];
  const float* bq = (const float*)d_in[2];
  const float* Wk = (const float*)d_in[3];
  const float* bk = (const float*)d_in[4];
  const float* Wv = (const float*)d_in[5];
  const float* bv = (const float*)d_in[6];
  const float* Wo = (const float*)d_in[7];
  const float* bo = (const float*)d_in[8];
  float* out = (float*)d_out;

  const size_t MT = (size_t)B_ * S_;            // 4096
  char* p = (char*)d_ws;
  u16* xb  = (u16*)p; p += MT * H_ * 2;         // reused as ctx buffer after QKV
  u16* Wqb = (u16*)p; p += (size_t)H_ * H_ * 2;
  u16* Wkb = (u16*)p; p += (size_t)H_ * H_ * 2;
  u16* Wvb = (u16*)p; p += (size_t)H_ * H_ * 2;
  u16* Wob = (u16*)p; p += (size_t)H_ * H_ * 2;
  u16* Qb  = (u16*)p; p += MT * H_ * 2;
  u16* Kb  = (u16*)p; p += MT * H_ * 2;
  u16* Vb  = (u16*)p; p += MT * H_ * 2;
  u16* Cb  = xb;

  cvt_bf16<<<(int)(MT * H_ / 1024), 256, 0, stream>>>(x,  xb,  (int)(MT * H_));
  cvt_bf16<<<H_ * H_ / 1024, 256, 0, stream>>>(Wq, Wqb, H_ * H_);
  cvt_bf16<<<H_ * H_ / 1024, 256, 0, stream>>>(Wk, Wkb, H_ * H_);
  cvt_bf16<<<H_ * H_ / 1024, 256, 0, stream>>>(Wv, Wvb, H_ * H_);
  cvt_bf16<<<H_ * H_ / 1024, 256, 0, stream>>>(Wo, Wob, H_ * H_);

  // fused QKV projection; Q pre-scaled by log2(e)/sqrt(HD) for exp2-domain softmax
  const float qscale = 0.125f * 1.44269504088896f;
  gemm_qkv<<<dim3(MT / 128, 24), 256, 0, stream>>>(xb, Wqb, Wkb, Wvb, bq, bk, bv,
                                                   Qb, Kb, Vb, (int)MT, H_, qscale);

  attn_fwd<<<dim3(S_ / 64 * NH_ * B_), 256, 0, stream>>>(Qb, Kb, Vb, Cb);

  // output projection: BM=64 -> 512 blocks (2/CU)
  gemm_bt<2, float><<<dim3(MT / 64, H_ / 128), 256, 0, stream>>>(Cb, Wob, bo, out,
                                                                 (int)MT, H_, H_, 1.0f);
}

// Round 3
// 135.818 us; speedup vs baseline: 2.4711x; 1.3803x over previous
//
#include <hip/hip_runtime.h>
#include <hip/hip_bf16.h>

#define B_  2
#define S_  2048
#define H_  1024
#define NH_ 16
#define HD_ 64

typedef unsigned short u16;
typedef unsigned int   u32;
typedef __attribute__((ext_vector_type(4))) float  f32x4;
typedef __attribute__((ext_vector_type(8))) __bf16 bf16x8;
typedef __attribute__((ext_vector_type(8))) unsigned short u16x8;
typedef __attribute__((ext_vector_type(4))) unsigned short u16x4;

// f32 -> bf16, round-to-nearest-even
__device__ __forceinline__ u16 f2bf(float f) {
  unsigned u = __builtin_bit_cast(unsigned, f);
  u += 0x7fffu + ((u >> 16) & 1u);
  return (u16)(u >> 16);
}

// async global->LDS, 16B per lane; LDS dest = wave-uniform base + lane*16
__device__ __forceinline__ void gload_lds16(const void* g, void* l) {
  __builtin_amdgcn_global_load_lds(
      (const __attribute__((address_space(1))) void*)g,
      (__attribute__((address_space(3))) void*)l, 16, 0, 0);
}

__global__ __launch_bounds__(256) void cvt_bf16(const float* __restrict__ in,
                                                u16* __restrict__ out, int n) {
  int i = (blockIdx.x * blockDim.x + threadIdx.x) * 4;
  if (i >= n) return;
  float4 v = *reinterpret_cast<const float4*>(in + i);
  u16x4 o;
  o[0] = f2bf(v.x); o[1] = f2bf(v.y); o[2] = f2bf(v.z); o[3] = f2bf(v.w);
  *reinterpret_cast<u16x4*>(out + i) = o;
}

__device__ __forceinline__ void store_out(float* C, size_t idx, float v) { C[idx] = v; }
__device__ __forceinline__ void store_out(u16* C, size_t idx, float v) { C[idx] = f2bf(v); }

// ---------------- GEMM core: C[m,n] = (sum_k A[m,k]*Bw[n,k] + bias[n]) * oscale
template <int MI, typename OutT>
__device__ __forceinline__ void gemm_core(const u16* __restrict__ A, const u16* __restrict__ Bw,
                                          const float* __restrict__ bias, OutT* __restrict__ C,
                                          int M, int N, int K, float oscale, int m0, int n0,
                                          u16* lsA, u16* lsB) {
  const int t = threadIdx.x;
  const int w = t >> 6, lane = t & 63;
  const int g = lane >> 4, c = lane & 15;
  const int wr = w >> 1, wc = w & 1;

  f32x4 acc[MI][4] = {};
  const int rowS = w * 16 + (lane >> 2);
  const int colS = (lane & 3) * 8;

  for (int k0 = 0; k0 < K; k0 += 32) {
    __syncthreads();
#pragma unroll
    for (int r = 0; r < MI / 2; ++r)
      gload_lds16(A + (size_t)(m0 + r * 64 + rowS) * K + k0 + colS, lsA + r * 2048 + w * 512);
#pragma unroll
    for (int r = 0; r < 2; ++r)
      gload_lds16(Bw + (size_t)(n0 + r * 64 + rowS) * K + k0 + colS, lsB + r * 2048 + w * 512);
    asm volatile("s_waitcnt vmcnt(0)" ::: "memory");
    __syncthreads();

    bf16x8 af[MI], bfr[4];
#pragma unroll
    for (int mi = 0; mi < MI; ++mi)
      af[mi] = *reinterpret_cast<const bf16x8*>(&lsA[(wr * (MI * 16) + mi * 16 + c) * 32 + g * 8]);
#pragma unroll
    for (int ni = 0; ni < 4; ++ni)
      bfr[ni] = *reinterpret_cast<const bf16x8*>(&lsB[(wc * 64 + ni * 16 + c) * 32 + g * 8]);
#pragma unroll
    for (int mi = 0; mi < MI; ++mi)
#pragma unroll
      for (int ni = 0; ni < 4; ++ni)
        acc[mi][ni] = __builtin_amdgcn_mfma_f32_16x16x32_bf16(af[mi], bfr[ni], acc[mi][ni], 0, 0, 0);
  }

#pragma unroll
  for (int mi = 0; mi < MI; ++mi) {
    int rowb = m0 + wr * (MI * 16) + mi * 16 + g * 4;
#pragma unroll
    for (int ni = 0; ni < 4; ++ni) {
      int col = n0 + wc * 64 + ni * 16 + c;
      float bv = bias[col];
#pragma unroll
      for (int r = 0; r < 4; ++r) {
        float v = (acc[mi][ni][r] + bv) * oscale;
        store_out(C, (size_t)(rowb + r) * N + col, v);
      }
    }
  }
}

template <int MI, typename OutT>
__global__ __launch_bounds__(256) void gemm_bt(const u16* __restrict__ A, const u16* __restrict__ Bw,
                                               const float* __restrict__ bias, OutT* __restrict__ C,
                                               int M, int N, int K, float oscale) {
  __shared__ u16 lsA[MI * 1024];
  __shared__ u16 lsB[4096];
  gemm_core<MI, OutT>(A, Bw, bias, C, M, N, K, oscale,
                      blockIdx.x * (MI * 32), blockIdx.y * 128, lsA, lsB);
}

__global__ __launch_bounds__(256) void gemm_qkv(const u16* __restrict__ xb,
                                                const u16* __restrict__ Wq, const u16* __restrict__ Wk,
                                                const u16* __restrict__ Wv,
                                                const float* __restrict__ bq, const float* __restrict__ bk,
                                                const float* __restrict__ bv,
                                                u16* __restrict__ Q, u16* __restrict__ Kb, u16* __restrict__ Vb,
                                                int M, int K, float qscale) {
  __shared__ u16 lsA[4096];
  __shared__ u16 lsB[4096];
  const int m0 = blockIdx.x * 128;
  const int ng = blockIdx.y * 128;
  const int sel = ng >> 10, n0 = ng & 1023;
  const u16*  W    = sel == 0 ? Wq : sel == 1 ? Wk : Wv;
  const float* bia = sel == 0 ? bq : sel == 1 ? bk : bv;
  u16*        Cp   = sel == 0 ? Q  : sel == 1 ? Kb : Vb;
  float os = sel == 0 ? qscale : 1.0f;
  gemm_core<4, u16>(xb, W, bia, Cp, M, 1024, K, os, m0, n0, lsA, lsB);
}

// ---------------- Flash attention, causal, swapped-QK^T, single barrier/tile.
// Grid: 512 blocks (XCD-swizzled); block processes q-tiles {31-j, j} (uniform work).
// Q pre-scaled by log2(e)/8 -> exp2-domain softmax.
__device__ __forceinline__ void stage_k(const u16* __restrict__ Kg, size_t headoff, int kvb,
                                        int kRow0, int kColB, int w, u16* lsKbuf) {
#pragma unroll
  for (int r = 0; r < 2; ++r)
    gload_lds16((const char*)(Kg + headoff + (size_t)(kvb + r * 32 + kRow0) * H_) + kColB,
                (char*)lsKbuf + r * 4096 + w * 1024);
}
__device__ __forceinline__ void load_v(const u16* __restrict__ Vg, size_t headoff, int kvb,
                                       int vKv, int vD0, u16x4* vr) {
#pragma unroll
  for (int r = 0; r < 2; ++r) {
    const u16* vb = Vg + headoff + (size_t)(kvb + r * 32 + vKv) * H_ + vD0;
    vr[2 * r]     = *reinterpret_cast<const u16x4*>(vb);
    vr[2 * r + 1] = *reinterpret_cast<const u16x4*>(vb + H_);
  }
}

__global__ __launch_bounds__(256) void attn_fwd(const u16* __restrict__ Qg,
                                                const u16* __restrict__ Kg,
                                                const u16* __restrict__ Vg,
                                                u16* __restrict__ Og) {
  __shared__ u16 lsK[2][64 * 64];    // [kv][d], 128B rows, XOR-swizzled content (dbuf)
  __shared__ u16 lsVt[2][64 * 72];   // [d][kv ^ 8*((d>>3)&7)], stride 72 (dbuf)
  __shared__ u16 lsP[4][16 * 72];    // per-wave P [16 q][64 kv], stride 72

  const int blk = blockIdx.x;
  const int wg  = (blk & 7) * 64 + (blk >> 3);      // 512 = 8 XCD x 64
  const int j = wg & 15, h = (wg >> 4) & 15, b = wg >> 8;

  const int t = threadIdx.x, w = t >> 6, lane = t & 63;
  const int g = lane >> 4, c = lane & 15;
  const size_t headoff = (size_t)b * (S_ * H_) + (size_t)h * HD_;

  // K staging: linear LDS dest, inverse-swizzled global source
  const int kO    = w * 1024 + lane * 16;
  const int kRow0 = kO >> 7;
  const int kColB = (kO & 127) ^ ((kRow0 & 7) << 4);
  // V staging: thread -> kv pair (2*(t>>4) + 32r), d block 4*(t&15)
  const int vKv = 2 * (t >> 4);
  const int vD0 = 4 * (t & 15);
  const int vS  = 8 * ((vD0 >> 3) & 7);

  for (int ti = 0; ti < 2; ++ti) {
    const int qt = ti ? j : 31 - j;
    const int q0 = qt * 64 + w * 16;
    const int nt = qt + 1;

    bf16x8 aq0 = *reinterpret_cast<const bf16x8*>(Qg + headoff + (size_t)(q0 + c) * H_ + g * 8);
    bf16x8 aq1 = *reinterpret_cast<const bf16x8*>(Qg + headoff + (size_t)(q0 + c) * H_ + 32 + g * 8);

    f32x4 oacc[4] = {};
    float mrun = -1e30f, lrun = 0.f;
    u16x4 vn[4];

    // prologue: stage tile 0
    load_v(Vg, headoff, 0, vKv, vD0, vn);
    stage_k(Kg, headoff, 0, kRow0, kColB, w, lsK[0]);
    asm volatile("s_waitcnt vmcnt(2)" ::: "memory");   // V regs ready (K gloads in flight)
#pragma unroll
    for (int r = 0; r < 2; ++r) {
      int kvx = (r * 32 + vKv) ^ vS;
#pragma unroll
      for (int dd = 0; dd < 4; ++dd) {
        u32 pr = (u32)vn[2 * r][dd] | ((u32)vn[2 * r + 1][dd] << 16);
        *reinterpret_cast<u32*>(&lsVt[0][(vD0 + dd) * 72 + kvx]) = pr;
      }
    }
    __syncthreads();   // drains K(0) gload + Vt writes visible

    for (int kt = 0; kt < nt; ++kt) {
      const int cur = kt & 1;
      const int kv0 = kt * 64;
      const bool st = (kt + 1 < nt);
      if (st) {
        load_v(Vg, headoff, kv0 + 64, vKv, vD0, vn);            // V loads first
        stage_k(Kg, headoff, kv0 + 64, kRow0, kColB, w, lsK[cur ^ 1]); // then K gloads
      }

      // QK^T (swapped): A = K rows, B = Q -> D[kv=4g+r][q=c]
      f32x4 sc[4];
#pragma unroll
      for (int nj = 0; nj < 4; ++nj) {
        int krow = nj * 16 + c;
        int sw = (krow & 7) << 4;
        const char* base = (const char*)lsK[cur] + krow * 128;
        bf16x8 ak0 = *reinterpret_cast<const bf16x8*>(base + ((g * 16) ^ sw));
        bf16x8 ak1 = *reinterpret_cast<const bf16x8*>(base + ((64 + g * 16) ^ sw));
        f32x4 z = {};
        z = __builtin_amdgcn_mfma_f32_16x16x32_bf16(ak0, aq0, z, 0, 0, 0);
        z = __builtin_amdgcn_mfma_f32_16x16x32_bf16(ak1, aq1, z, 0, 0, 0);
        sc[nj] = z;
      }

      // causal mask: only the diagonal tile
      if (kt == qt) {
#pragma unroll
        for (int nj = 0; nj < 4; ++nj)
#pragma unroll
          for (int r = 0; r < 4; ++r) {
            int kv = kv0 + nj * 16 + 4 * g + r;
            sc[nj][r] = (kv > q0 + c) ? -1e30f : sc[nj][r];
          }
      }

      // tile max per q (=c): in-lane tree + 2 shfl over g-groups
      f32x4 mv = sc[0];
#pragma unroll
      for (int nj = 1; nj < 4; ++nj) {
        mv[0] = fmaxf(mv[0], sc[nj][0]); mv[1] = fmaxf(mv[1], sc[nj][1]);
        mv[2] = fmaxf(mv[2], sc[nj][2]); mv[3] = fmaxf(mv[3], sc[nj][3]);
      }
      float pm = fmaxf(fmaxf(mv[0], mv[1]), fmaxf(mv[2], mv[3]));
      pm = fmaxf(pm, __shfl_xor(pm, 16));
      pm = fmaxf(pm, __shfl_xor(pm, 32));

      // defer-max: rescale only when max grew by > 8 (exp2 domain)
      if (!__all(pm <= mrun + 8.0f)) {
        float mn  = fmaxf(mrun, pm);
        float s8  = exp2f(mrun - mn);
        mrun = mn;
        lrun *= s8;
#pragma unroll
        for (int r = 0; r < 4; ++r) {
          float sr = __shfl(s8, 4 * g + r);   // scale of q-row 4g+r
#pragma unroll
          for (int dt = 0; dt < 4; ++dt) oacc[dt][r] *= sr;
        }
      }

      // overlap: V(kt+1) regs -> lsVt[cur^1]  (2 K gloads still in flight)
      if (st) {
        asm volatile("s_waitcnt vmcnt(2)" ::: "memory");
#pragma unroll
        for (int r = 0; r < 2; ++r) {
          int kvx = (r * 32 + vKv) ^ vS;
#pragma unroll
          for (int dd = 0; dd < 4; ++dd) {
            u32 pr = (u32)vn[2 * r][dd] | ((u32)vn[2 * r + 1][dd] << 16);
            *reinterpret_cast<u32*>(&lsVt[cur ^ 1][(vD0 + dd) * 72 + kvx]) = pr;
          }
        }
      }

      // P = exp2(sc - m), row-sum, pack bf16
      float rs = 0.f;
      u16x4 pk[4];
#pragma unroll
      for (int nj = 0; nj < 4; ++nj)
#pragma unroll
        for (int r = 0; r < 4; ++r) {
          float pv = exp2f(sc[nj][r] - mrun);
          pk[nj][r] = f2bf(pv);
          rs += pv;
        }
      rs += __shfl_xor(rs, 16);
      rs += __shfl_xor(rs, 32);
      lrun += rs;

      // P roundtrip: [kv][q] -> [q][kv] A-frag via per-wave LDS
#pragma unroll
      for (int nj = 0; nj < 4; ++nj)
        *reinterpret_cast<u16x4*>(&lsP[w][c * 72 + 16 * nj + 4 * g]) = pk[nj];
      asm volatile("s_waitcnt lgkmcnt(0)" ::: "memory");
      __builtin_amdgcn_sched_barrier(0);
      bf16x8 pa0 = *reinterpret_cast<const bf16x8*>(&lsP[w][c * 72 + g * 8]);
      bf16x8 pa1 = *reinterpret_cast<const bf16x8*>(&lsP[w][c * 72 + 32 + g * 8]);

      // PV
#pragma unroll
      for (int dt = 0; dt < 4; ++dt) {
        int d = dt * 16 + c;
        int sx = ((d >> 3) & 7) << 4;
        const char* vb = (const char*)&lsVt[cur][d * 72];
        bf16x8 bv0 = *reinterpret_cast<const bf16x8*>(vb + ((g * 16) ^ sx));
        bf16x8 bv1 = *reinterpret_cast<const bf16x8*>(vb + ((64 + g * 16) ^ sx));
        oacc[dt] = __builtin_amdgcn_mfma_f32_16x16x32_bf16(pa0, bv0, oacc[dt], 0, 0, 0);
        oacc[dt] = __builtin_amdgcn_mfma_f32_16x16x32_bf16(pa1, bv1, oacc[dt], 0, 0, 0);
      }

      __syncthreads();   // K(kt+1) drained; Vt(kt+1) visible; buffers released
    }

    // epilogue: O[q][d] = oacc / l   (oacc row q = 4g+r, col d = 16dt+c)
#pragma unroll
    for (int r = 0; r < 4; ++r) {
      float lq  = __shfl(lrun, 4 * g + r);
      float inv = 1.f / lq;
      int qrow  = q0 + 4 * g + r;
#pragma unroll
      for (int dt = 0; dt < 4; ++dt)
        Og[headoff + (size_t)qrow * H_ + dt * 16 + c] = f2bf(oacc[dt][r] * inv);
    }
  }
}

extern "C" void kernel_launch(void* const* d_in, const int* in_sizes, int n_in,
                              void* d_out, int out_size, void* d_ws, size_t ws_size,
                              hipStream_t stream) {
  const float* x  = (const float*)d_in[0];
  const float* Wq = (const float*)d_in[1];
  const float* bq = (const float*)d_in[2];
  const float* Wk = (const float*)d_in[3];
  const float* bk = (const float*)d_in[4];
  const float* Wv = (const float*)d_in[5];
  const float* bv = (const float*)d_in[6];
  const float* Wo = (const float*)d_in[7];
  const float* bo = (const float*)d_in[8];
  float* out = (float*)d_out;

  const size_t MT = (size_t)B_ * S_;            // 4096
  char* p = (char*)d_ws;
  u16* xb  = (u16*)p; p += MT * H_ * 2;         // reused as ctx buffer after QKV
  u16* Wqb = (u16*)p; p += (size_t)H_ * H_ * 2;
  u16* Wkb = (u16*)p; p += (size_t)H_ * H_ * 2;
  u16* Wvb = (u16*)p; p += (size_t)H_ * H_ * 2;
  u16* Wob = (u16*)p; p += (size_t)H_ * H_ * 2;
  u16* Qb  = (u16*)p; p += MT * H_ * 2;
  u16* Kb  = (u16*)p; p += MT * H_ * 2;
  u16* Vb  = (u16*)p; p += MT * H_ * 2;
  u16* Cb  = xb;

  cvt_bf16<<<(int)(MT * H_ / 1024), 256, 0, stream>>>(x,  xb,  (int)(MT * H_));
  cvt_bf16<<<H_ * H_ / 1024, 256, 0, stream>>>(Wq, Wqb, H_ * H_);
  cvt_bf16<<<H_ * H_ / 1024, 256, 0, stream>>>(Wk, Wkb, H_ * H_);
  cvt_bf16<<<H_ * H_ / 1024, 256, 0, stream>>>(Wv, Wvb, H_ * H_);
  cvt_bf16<<<H_ * H_ / 1024, 256, 0, stream>>>(Wo, Wob, H_ * H_);

  const float qscale = 0.125f * 1.44269504088896f;  // log2(e)/sqrt(HD)
  gemm_qkv<<<dim3(MT / 128, 24), 256, 0, stream>>>(xb, Wqb, Wkb, Wvb, bq, bk, bv,
                                                   Qb, Kb, Vb, (int)MT, H_, qscale);

  attn_fwd<<<dim3(512), 256, 0, stream>>>(Qb, Kb, Vb, Cb);

  gemm_bt<2, float><<<dim3(MT / 64, H_ / 128), 256, 0, stream>>>(Cb, Wob, bo, out,
                                                                 (int)MT, H_, H_, 1.0f);
}

// Round 4
// 115.578 us; speedup vs baseline: 2.9038x; 1.1751x over previous
//
#include <hip/hip_runtime.h>
#include <hip/hip_bf16.h>

#define B_  2
#define S_  2048
#define H_  1024
#define NH_ 16
#define HD_ 64

typedef unsigned short u16;
typedef unsigned int   u32;
typedef __attribute__((ext_vector_type(4))) float  f32x4;
typedef __attribute__((ext_vector_type(8))) __bf16 bf16x8;
typedef __attribute__((ext_vector_type(2))) unsigned int u32x2;
typedef __attribute__((ext_vector_type(4))) unsigned short u16x4;

// f32 -> bf16 RNE (scalar, epilogue use)
__device__ __forceinline__ u16 f2bf(float f) {
  unsigned u = __builtin_bit_cast(unsigned, f);
  u += 0x7fffu + ((u >> 16) & 1u);
  return (u16)(u >> 16);
}
// packed f32x2 -> bf16x2 (one VALU op)
__device__ __forceinline__ u32 cvtpk(float lo, float hi) {
  u32 r;
  asm("v_cvt_pk_bf16_f32 %0, %1, %2" : "=v"(r) : "v"(lo), "v"(hi));
  return r;
}
// 2^x via v_exp_f32 (one TRANS op)
__device__ __forceinline__ float ex2(float x) {
  float r;
  asm("v_exp_f32 %0, %1" : "=v"(r) : "v"(x));
  return r;
}

// async global->LDS, 16B per lane
__device__ __forceinline__ void gload_lds16(const void* g, void* l) {
  __builtin_amdgcn_global_load_lds(
      (const __attribute__((address_space(1))) void*)g,
      (__attribute__((address_space(3))) void*)l, 16, 0, 0);
}

// Fused f32->bf16 conversion of x + 4 weight matrices (one launch)
#define NX_ (4u * 1024u * 1024u)
__global__ __launch_bounds__(256) void cvt_all(const float* __restrict__ x,
                                               const float* __restrict__ w0, const float* __restrict__ w1,
                                               const float* __restrict__ w2, const float* __restrict__ w3,
                                               u16* __restrict__ xb,
                                               u16* __restrict__ o0, u16* __restrict__ o1,
                                               u16* __restrict__ o2, u16* __restrict__ o3) {
  size_t i4 = ((size_t)blockIdx.x * 256 + threadIdx.x) * 4;
  const float* src; u16* dst; size_t off;
  if (i4 < (size_t)NX_) { src = x; dst = xb; off = i4; }
  else {
    size_t j = i4 - NX_;
    int seg = (int)(j >> 20);
    off = j & ((1u << 20) - 1);
    src = seg == 0 ? w0 : seg == 1 ? w1 : seg == 2 ? w2 : w3;
    dst = seg == 0 ? o0 : seg == 1 ? o1 : seg == 2 ? o2 : o3;
  }
  float4 v = *reinterpret_cast<const float4*>(src + off);
  u16x4 o;
  o[0] = f2bf(v.x); o[1] = f2bf(v.y); o[2] = f2bf(v.z); o[3] = f2bf(v.w);
  *reinterpret_cast<u16x4*>(dst + off) = o;
}

__device__ __forceinline__ void store_out(float* C, size_t idx, float v) { C[idx] = v; }
__device__ __forceinline__ void store_out(u16* C, size_t idx, float v) { C[idx] = f2bf(v); }

// ---------------- GEMM core: C[m,n] = (sum_k A[m,k]*Bw[n,k] + bias[n]) * oscale
template <int MI, typename OutT>
__device__ __forceinline__ void gemm_core(const u16* __restrict__ A, const u16* __restrict__ Bw,
                                          const float* __restrict__ bias, OutT* __restrict__ C,
                                          int M, int N, int K, float oscale, int m0, int n0,
                                          u16* lsA, u16* lsB) {
  const int t = threadIdx.x;
  const int w = t >> 6, lane = t & 63;
  const int g = lane >> 4, c = lane & 15;
  const int wr = w >> 1, wc = w & 1;

  f32x4 acc[MI][4] = {};
  const int rowS = w * 16 + (lane >> 2);
  const int colS = (lane & 3) * 8;

  for (int k0 = 0; k0 < K; k0 += 32) {
    __syncthreads();
#pragma unroll
    for (int r = 0; r < MI / 2; ++r)
      gload_lds16(A + (size_t)(m0 + r * 64 + rowS) * K + k0 + colS, lsA + r * 2048 + w * 512);
#pragma unroll
    for (int r = 0; r < 2; ++r)
      gload_lds16(Bw + (size_t)(n0 + r * 64 + rowS) * K + k0 + colS, lsB + r * 2048 + w * 512);
    asm volatile("s_waitcnt vmcnt(0)" ::: "memory");
    __syncthreads();

    bf16x8 af[MI], bfr[4];
#pragma unroll
    for (int mi = 0; mi < MI; ++mi)
      af[mi] = *reinterpret_cast<const bf16x8*>(&lsA[(wr * (MI * 16) + mi * 16 + c) * 32 + g * 8]);
#pragma unroll
    for (int ni = 0; ni < 4; ++ni)
      bfr[ni] = *reinterpret_cast<const bf16x8*>(&lsB[(wc * 64 + ni * 16 + c) * 32 + g * 8]);
#pragma unroll
    for (int mi = 0; mi < MI; ++mi)
#pragma unroll
      for (int ni = 0; ni < 4; ++ni)
        acc[mi][ni] = __builtin_amdgcn_mfma_f32_16x16x32_bf16(af[mi], bfr[ni], acc[mi][ni], 0, 0, 0);
  }

#pragma unroll
  for (int mi = 0; mi < MI; ++mi) {
    int rowb = m0 + wr * (MI * 16) + mi * 16 + g * 4;
#pragma unroll
    for (int ni = 0; ni < 4; ++ni) {
      int col = n0 + wc * 64 + ni * 16 + c;
      float bv = bias[col];
#pragma unroll
      for (int r = 0; r < 4; ++r) {
        float v = (acc[mi][ni][r] + bv) * oscale;
        store_out(C, (size_t)(rowb + r) * N + col, v);
      }
    }
  }
}

// Fused QKV projection: 1D grid 768, XCD-chunked (each XCD: 4 m-panels x 24 n-tiles)
__global__ __launch_bounds__(256) void gemm_qkv(const u16* __restrict__ xb,
                                                const u16* __restrict__ Wq, const u16* __restrict__ Wk,
                                                const u16* __restrict__ Wv,
                                                const float* __restrict__ bq, const float* __restrict__ bk,
                                                const float* __restrict__ bv,
                                                u16* __restrict__ Q, u16* __restrict__ Kb, u16* __restrict__ Vb,
                                                int M, int K, float qscale) {
  __shared__ u16 lsA[4096];
  __shared__ u16 lsB[4096];
  const int fid = blockIdx.x;
  const int xcd = fid & 7, i = fid >> 3;        // i in 0..95
  const int mloc = i / 24, nn = i % 24;
  const int m0 = (xcd * 4 + mloc) * 128;
  const int ng = nn * 128;
  const int sel = ng >> 10, n0 = ng & 1023;
  const u16*  W    = sel == 0 ? Wq : sel == 1 ? Wk : Wv;
  const float* bia = sel == 0 ? bq : sel == 1 ? bk : bv;
  u16*        Cp   = sel == 0 ? Q  : sel == 1 ? Kb : Vb;
  float os = sel == 0 ? qscale : 1.0f;
  gemm_core<4, u16>(xb, W, bia, Cp, M, 1024, K, os, m0, n0, lsA, lsB);
}

// Output projection: 1D grid 512, XCD-chunked (each XCD: 8 m-panels x 8 n-tiles), BM=64
__global__ __launch_bounds__(256) void gemm_wo(const u16* __restrict__ A, const u16* __restrict__ Bw,
                                               const float* __restrict__ bias, float* __restrict__ C,
                                               int M, int N, int K) {
  __shared__ u16 lsA[2048];
  __shared__ u16 lsB[4096];
  const int fid = blockIdx.x;
  const int xcd = fid & 7, i = fid >> 3;        // 0..63
  const int mloc = i >> 3, nn = i & 7;
  const int m0 = (xcd * 8 + mloc) * 64;
  const int n0 = nn * 128;
  gemm_core<2, float>(A, Bw, bias, C, M, N, K, 1.0f, m0, n0, lsA, lsB);
}

// ---------------- Flash attention, causal, swapped-QK^T.
// Grid: 1024 blocks, 1 q-tile each, heavy-qt-first, XCD gets 4 whole (b,h) pairs.
// Q pre-scaled by log2(e)/8 -> exp2-domain softmax.
__device__ __forceinline__ void stage_k(const u16* __restrict__ Kg, size_t headoff, int kvb,
                                        int kRow0, int kColB, int w, u16* lsKbuf) {
#pragma unroll
  for (int r = 0; r < 2; ++r)
    gload_lds16((const char*)(Kg + headoff + (size_t)(kvb + r * 32 + kRow0) * H_) + kColB,
                (char*)lsKbuf + r * 4096 + w * 1024);
}

__global__ __launch_bounds__(256) void attn_fwd(const u16* __restrict__ Qg,
                                                const u16* __restrict__ Kg,
                                                const u16* __restrict__ Vg,
                                                u16* __restrict__ Og) {
  __shared__ u16 lsK[2][64 * 64];    // [kv][d], 128B rows, XOR-swizzled content (dbuf)
  __shared__ u16 lsVt[2][64 * 72];   // [d][kv ^ 8*((d>>3)&7)], stride 72 (dbuf)
  __shared__ u16 lsP[4][16 * 72];    // per-wave P [16 q][64 kv], stride 72

  const int blk = blockIdx.x;
  const int xcd = blk & 7, i = blk >> 3;        // i: 0..127
  const int pair = i & 3;
  const int qt = 31 - (i >> 2);                  // heavy tiles dispatch first
  const int bh = xcd * 4 + pair;
  const int h = bh & 15, b = bh >> 4;

  const int t = threadIdx.x, w = t >> 6, lane = t & 63;
  const int g = lane >> 4, c = lane & 15;
  const size_t headoff = (size_t)b * (S_ * H_) + (size_t)h * HD_;
  const int q0 = qt * 64 + w * 16;
  const int nt = qt + 1;

  // K staging: linear LDS dest, inverse-swizzled global source
  const int kO    = w * 1024 + lane * 16;
  const int kRow0 = kO >> 7;
  const int kColB = (kO & 127) ^ ((kRow0 & 7) << 4);
  // V staging: thread -> kv pair (2*(t>>4) + 32r), d block 4*(t&15)
  const int vKv = 2 * (t >> 4);
  const int vD0 = 4 * (t & 15);
  const int vS  = 8 * ((vD0 >> 3) & 7);

  // hoisted LDS byte offsets (per-lane constants)
  int qkOff[4][2], pvOff[4][2];
#pragma unroll
  for (int nj = 0; nj < 4; ++nj) {
    int krow = nj * 16 + c, sw = (krow & 7) << 4;
    qkOff[nj][0] = krow * 128 + ((g * 16) ^ sw);
    qkOff[nj][1] = krow * 128 + ((64 + g * 16) ^ sw);
  }
#pragma unroll
  for (int dt = 0; dt < 4; ++dt) {
    int d = dt * 16 + c, sx = ((d >> 3) & 7) << 4;
    pvOff[dt][0] = d * 144 + ((g * 16) ^ sx);
    pvOff[dt][1] = d * 144 + ((64 + g * 16) ^ sx);
  }

  bf16x8 aq0 = *reinterpret_cast<const bf16x8*>(Qg + headoff + (size_t)(q0 + c) * H_ + g * 8);
  bf16x8 aq1 = *reinterpret_cast<const bf16x8*>(Qg + headoff + (size_t)(q0 + c) * H_ + 32 + g * 8);

  f32x4 oacc[4] = {};
  float mrun = -1e30f, lrun = 0.f;
  u32x2 vlo[2], vhi[2];

  // prologue: stage tile 0
#pragma unroll
  for (int r = 0; r < 2; ++r) {
    const u16* vp = Vg + headoff + (size_t)(r * 32 + vKv) * H_ + vD0;
    vlo[r] = *reinterpret_cast<const u32x2*>(vp);
    vhi[r] = *reinterpret_cast<const u32x2*>(vp + H_);
  }
  stage_k(Kg, headoff, 0, kRow0, kColB, w, lsK[0]);
  asm volatile("s_waitcnt vmcnt(2)" ::: "memory");   // V regs ready, K gloads in flight
#pragma unroll
  for (int r = 0; r < 2; ++r) {
    int kvx = (r * 32 + vKv) ^ vS;
    u32 w0 = __builtin_amdgcn_perm(vhi[r][0], vlo[r][0], 0x05040100u);
    u32 w1 = __builtin_amdgcn_perm(vhi[r][0], vlo[r][0], 0x07060302u);
    u32 w2 = __builtin_amdgcn_perm(vhi[r][1], vlo[r][1], 0x05040100u);
    u32 w3 = __builtin_amdgcn_perm(vhi[r][1], vlo[r][1], 0x07060302u);
    *reinterpret_cast<u32*>(&lsVt[0][(vD0 + 0) * 72 + kvx]) = w0;
    *reinterpret_cast<u32*>(&lsVt[0][(vD0 + 1) * 72 + kvx]) = w1;
    *reinterpret_cast<u32*>(&lsVt[0][(vD0 + 2) * 72 + kvx]) = w2;
    *reinterpret_cast<u32*>(&lsVt[0][(vD0 + 3) * 72 + kvx]) = w3;
  }
  __syncthreads();   // K(0) drained (barrier implies vmcnt(0)), Vt(0) visible

  for (int kt = 0; kt < nt; ++kt) {
    const int cur = kt & 1;
    const int kv0 = kt * 64;
    const bool st = (kt + 1 < nt);
    if (st) {
#pragma unroll
      for (int r = 0; r < 2; ++r) {
        const u16* vp = Vg + headoff + (size_t)(kv0 + 64 + r * 32 + vKv) * H_ + vD0;
        vlo[r] = *reinterpret_cast<const u32x2*>(vp);
        vhi[r] = *reinterpret_cast<const u32x2*>(vp + H_);
      }
      stage_k(Kg, headoff, kv0 + 64, kRow0, kColB, w, lsK[cur ^ 1]);
    }

    // QK^T (swapped): D[kv=4g+r + 16nj][q=c]
    const char* kb = (const char*)lsK[cur];
    f32x4 sc[4];
#pragma unroll
    for (int nj = 0; nj < 4; ++nj) {
      bf16x8 ak0 = *reinterpret_cast<const bf16x8*>(kb + qkOff[nj][0]);
      bf16x8 ak1 = *reinterpret_cast<const bf16x8*>(kb + qkOff[nj][1]);
      f32x4 z = {};
      z = __builtin_amdgcn_mfma_f32_16x16x32_bf16(ak0, aq0, z, 0, 0, 0);
      z = __builtin_amdgcn_mfma_f32_16x16x32_bf16(ak1, aq1, z, 0, 0, 0);
      sc[nj] = z;
    }

    // causal mask: diagonal tile only
    if (kt == qt) {
#pragma unroll
      for (int nj = 0; nj < 4; ++nj)
#pragma unroll
        for (int r = 0; r < 4; ++r) {
          int kv = kv0 + nj * 16 + 4 * g + r;
          sc[nj][r] = (kv > q0 + c) ? -1e30f : sc[nj][r];
        }
    }

    // tile max per q(=c): in-lane tree + 2 shfl
    float m01 = fmaxf(fmaxf(sc[0][0], sc[0][1]), fmaxf(sc[0][2], sc[0][3]));
    float m23 = fmaxf(fmaxf(sc[1][0], sc[1][1]), fmaxf(sc[1][2], sc[1][3]));
    float m45 = fmaxf(fmaxf(sc[2][0], sc[2][1]), fmaxf(sc[2][2], sc[2][3]));
    float m67 = fmaxf(fmaxf(sc[3][0], sc[3][1]), fmaxf(sc[3][2], sc[3][3]));
    float pm = fmaxf(fmaxf(m01, m23), fmaxf(m45, m67));
    pm = fmaxf(pm, __shfl_xor(pm, 16));
    pm = fmaxf(pm, __shfl_xor(pm, 32));

    // defer-max: rescale only when max grew by > 8 (exp2 domain)
    if (!__all(pm <= mrun + 8.0f)) {
      float mn = fmaxf(mrun, pm);
      float s8 = ex2(mrun - mn);
      mrun = mn;
      lrun *= s8;
#pragma unroll
      for (int r = 0; r < 4; ++r) {
        float sr = __shfl(s8, 4 * g + r);
#pragma unroll
        for (int dt = 0; dt < 4; ++dt) oacc[dt][r] *= sr;
      }
    }

    // overlap: V(kt+1) regs -> lsVt[cur^1]  (K gloads still in flight)
    if (st) {
      asm volatile("s_waitcnt vmcnt(2)" ::: "memory");
#pragma unroll
      for (int r = 0; r < 2; ++r) {
        int kvx = (r * 32 + vKv) ^ vS;
        u32 w0 = __builtin_amdgcn_perm(vhi[r][0], vlo[r][0], 0x05040100u);
        u32 w1 = __builtin_amdgcn_perm(vhi[r][0], vlo[r][0], 0x07060302u);
        u32 w2 = __builtin_amdgcn_perm(vhi[r][1], vlo[r][1], 0x05040100u);
        u32 w3 = __builtin_amdgcn_perm(vhi[r][1], vlo[r][1], 0x07060302u);
        u16* vt = &lsVt[cur ^ 1][0];
        *reinterpret_cast<u32*>(&vt[(vD0 + 0) * 72 + kvx]) = w0;
        *reinterpret_cast<u32*>(&vt[(vD0 + 1) * 72 + kvx]) = w1;
        *reinterpret_cast<u32*>(&vt[(vD0 + 2) * 72 + kvx]) = w2;
        *reinterpret_cast<u32*>(&vt[(vD0 + 3) * 72 + kvx]) = w3;
      }
    }

    // P = exp2(sc - m): v_exp + cvt_pk, partial sums per nj
    float rsn[4];
    u32x2 pp[4];
#pragma unroll
    for (int nj = 0; nj < 4; ++nj) {
      float p0 = ex2(sc[nj][0] - mrun);
      float p1 = ex2(sc[nj][1] - mrun);
      float p2 = ex2(sc[nj][2] - mrun);
      float p3 = ex2(sc[nj][3] - mrun);
      rsn[nj] = (p0 + p1) + (p2 + p3);
      pp[nj][0] = cvtpk(p0, p1);
      pp[nj][1] = cvtpk(p2, p3);
    }
    float rs = (rsn[0] + rsn[1]) + (rsn[2] + rsn[3]);
    rs += __shfl_xor(rs, 16);
    rs += __shfl_xor(rs, 32);
    lrun += rs;

    // P roundtrip: [kv][q] -> [q][kv] A-frag via per-wave LDS (wave-local fence)
#pragma unroll
    for (int nj = 0; nj < 4; ++nj)
      *reinterpret_cast<u32x2*>(&lsP[w][c * 72 + 16 * nj + 4 * g]) = pp[nj];
    asm volatile("s_waitcnt lgkmcnt(0)" ::: "memory");
    __builtin_amdgcn_sched_barrier(0);
    bf16x8 pa0 = *reinterpret_cast<const bf16x8*>(&lsP[w][c * 72 + g * 8]);
    bf16x8 pa1 = *reinterpret_cast<const bf16x8*>(&lsP[w][c * 72 + 32 + g * 8]);

    // PV
    const char* vb = (const char*)lsVt[cur];
#pragma unroll
    for (int dt = 0; dt < 4; ++dt) {
      bf16x8 bv0 = *reinterpret_cast<const bf16x8*>(vb + pvOff[dt][0]);
      bf16x8 bv1 = *reinterpret_cast<const bf16x8*>(vb + pvOff[dt][1]);
      oacc[dt] = __builtin_amdgcn_mfma_f32_16x16x32_bf16(pa0, bv0, oacc[dt], 0, 0, 0);
      oacc[dt] = __builtin_amdgcn_mfma_f32_16x16x32_bf16(pa1, bv1, oacc[dt], 0, 0, 0);
    }

    __syncthreads();   // K(kt+1) drained; Vt(kt+1) visible; buffers released
  }

  // epilogue: O[q][d] = oacc / l
#pragma unroll
  for (int r = 0; r < 4; ++r) {
    float lq  = __shfl(lrun, 4 * g + r);
    float inv = 1.f / lq;
    int qrow  = q0 + 4 * g + r;
#pragma unroll
    for (int dt = 0; dt < 4; ++dt)
      Og[headoff + (size_t)qrow * H_ + dt * 16 + c] = f2bf(oacc[dt][r] * inv);
  }
}

extern "C" void kernel_launch(void* const* d_in, const int* in_sizes, int n_in,
                              void* d_out, int out_size, void* d_ws, size_t ws_size,
                              hipStream_t stream) {
  const float* x  = (const float*)d_in[0];
  const float* Wq = (const float*)d_in[1];
  const float* bq = (const float*)d_in[2];
  const float* Wk = (const float*)d_in[3];
  const float* bk = (const float*)d_in[4];
  const float* Wv = (const float*)d_in[5];
  const float* bv = (const float*)d_in[6];
  const float* Wo = (const float*)d_in[7];
  const float* bo = (const float*)d_in[8];
  float* out = (float*)d_out;

  const size_t MT = (size_t)B_ * S_;            // 4096
  char* p = (char*)d_ws;
  u16* xb  = (u16*)p; p += MT * H_ * 2;         // reused as ctx buffer after QKV
  u16* Wqb = (u16*)p; p += (size_t)H_ * H_ * 2;
  u16* Wkb = (u16*)p; p += (size_t)H_ * H_ * 2;
  u16* Wvb = (u16*)p; p += (size_t)H_ * H_ * 2;
  u16* Wob = (u16*)p; p += (size_t)H_ * H_ * 2;
  u16* Qb  = (u16*)p; p += MT * H_ * 2;
  u16* Kb  = (u16*)p; p += MT * H_ * 2;
  u16* Vb  = (u16*)p; p += MT * H_ * 2;
  u16* Cb  = xb;

  // fused conversions: x (4M elems) + 4 weights (1M each) = 8M elems
  cvt_all<<<8192, 256, 0, stream>>>(x, Wq, Wk, Wv, Wo, xb, Wqb, Wkb, Wvb, Wob);

  const float qscale = 0.125f * 1.44269504088896f;  // log2(e)/sqrt(HD)
  gemm_qkv<<<768, 256, 0, stream>>>(xb, Wqb, Wkb, Wvb, bq, bk, bv,
                                    Qb, Kb, Vb, (int)MT, H_, qscale);

  attn_fwd<<<1024, 256, 0, stream>>>(Qb, Kb, Vb, Cb);

  gemm_wo<<<512, 256, 0, stream>>>(Cb, Wob, bo, out, (int)MT, H_, H_);
}

// Round 5
// 113.206 us; speedup vs baseline: 2.9646x; 1.0210x over previous
//
#include <hip/hip_runtime.h>
#include <hip/hip_bf16.h>

#define B_  2
#define S_  2048
#define H_  1024
#define NH_ 16
#define HD_ 64

typedef unsigned short u16;
typedef unsigned int   u32;
typedef __attribute__((ext_vector_type(4)))  float  f32x4;
typedef __attribute__((ext_vector_type(16))) float  f32x16;
typedef __attribute__((ext_vector_type(8)))  __bf16 bf16x8;
typedef __attribute__((ext_vector_type(2)))  unsigned int u32x2;
typedef __attribute__((ext_vector_type(4)))  unsigned int u32x4;
typedef __attribute__((ext_vector_type(4)))  unsigned short u16x4;

// f32 -> bf16 RNE (scalar)
__device__ __forceinline__ u16 f2bf(float f) {
  unsigned u = __builtin_bit_cast(unsigned, f);
  u += 0x7fffu + ((u >> 16) & 1u);
  return (u16)(u >> 16);
}
// packed f32x2 -> bf16x2 (one VALU op)
__device__ __forceinline__ u32 cvtpk(float lo, float hi) {
  u32 r;
  asm("v_cvt_pk_bf16_f32 %0, %1, %2" : "=v"(r) : "v"(lo), "v"(hi));
  return r;
}
// 2^x via v_exp_f32
__device__ __forceinline__ float ex2(float x) {
  float r;
  asm("v_exp_f32 %0, %1" : "=v"(r) : "v"(x));
  return r;
}

// async global->LDS, 16B per lane
__device__ __forceinline__ void gload_lds16(const void* g, void* l) {
  __builtin_amdgcn_global_load_lds(
      (const __attribute__((address_space(1))) void*)g,
      (__attribute__((address_space(3))) void*)l, 16, 0, 0);
}

// Fused f32->bf16 conversion of x + 4 weight matrices (one launch)
#define NX_ (4u * 1024u * 1024u)
__global__ __launch_bounds__(256) void cvt_all(const float* __restrict__ x,
                                               const float* __restrict__ w0, const float* __restrict__ w1,
                                               const float* __restrict__ w2, const float* __restrict__ w3,
                                               u16* __restrict__ xb,
                                               u16* __restrict__ o0, u16* __restrict__ o1,
                                               u16* __restrict__ o2, u16* __restrict__ o3) {
  size_t i4 = ((size_t)blockIdx.x * 256 + threadIdx.x) * 4;
  const float* src; u16* dst; size_t off;
  if (i4 < (size_t)NX_) { src = x; dst = xb; off = i4; }
  else {
    size_t j = i4 - NX_;
    int seg = (int)(j >> 20);
    off = j & ((1u << 20) - 1);
    src = seg == 0 ? w0 : seg == 1 ? w1 : seg == 2 ? w2 : w3;
    dst = seg == 0 ? o0 : seg == 1 ? o1 : seg == 2 ? o2 : o3;
  }
  float4 v = *reinterpret_cast<const float4*>(src + off);
  u16x4 o;
  o[0] = f2bf(v.x); o[1] = f2bf(v.y); o[2] = f2bf(v.z); o[3] = f2bf(v.w);
  *reinterpret_cast<u16x4*>(dst + off) = o;
}

__device__ __forceinline__ void store_out(float* C, size_t idx, float v) { C[idx] = v; }
__device__ __forceinline__ void store_out(u16* C, size_t idx, float v) { C[idx] = f2bf(v); }

// ---------------- GEMM core: C[m,n] = (sum_k A[m,k]*Bw[n,k] + bias[n]) * oscale
template <int MI, typename OutT>
__device__ __forceinline__ void gemm_core(const u16* __restrict__ A, const u16* __restrict__ Bw,
                                          const float* __restrict__ bias, OutT* __restrict__ C,
                                          int M, int N, int K, float oscale, int m0, int n0,
                                          u16* lsA, u16* lsB) {
  const int t = threadIdx.x;
  const int w = t >> 6, lane = t & 63;
  const int g = lane >> 4, c = lane & 15;
  const int wr = w >> 1, wc = w & 1;

  f32x4 acc[MI][4] = {};
  const int rowS = w * 16 + (lane >> 2);
  const int colS = (lane & 3) * 8;

  for (int k0 = 0; k0 < K; k0 += 32) {
    __syncthreads();
#pragma unroll
    for (int r = 0; r < MI / 2; ++r)
      gload_lds16(A + (size_t)(m0 + r * 64 + rowS) * K + k0 + colS, lsA + r * 2048 + w * 512);
#pragma unroll
    for (int r = 0; r < 2; ++r)
      gload_lds16(Bw + (size_t)(n0 + r * 64 + rowS) * K + k0 + colS, lsB + r * 2048 + w * 512);
    asm volatile("s_waitcnt vmcnt(0)" ::: "memory");
    __syncthreads();

    bf16x8 af[MI], bfr[4];
#pragma unroll
    for (int mi = 0; mi < MI; ++mi)
      af[mi] = *reinterpret_cast<const bf16x8*>(&lsA[(wr * (MI * 16) + mi * 16 + c) * 32 + g * 8]);
#pragma unroll
    for (int ni = 0; ni < 4; ++ni)
      bfr[ni] = *reinterpret_cast<const bf16x8*>(&lsB[(wc * 64 + ni * 16 + c) * 32 + g * 8]);
#pragma unroll
    for (int mi = 0; mi < MI; ++mi)
#pragma unroll
      for (int ni = 0; ni < 4; ++ni)
        acc[mi][ni] = __builtin_amdgcn_mfma_f32_16x16x32_bf16(af[mi], bfr[ni], acc[mi][ni], 0, 0, 0);
  }

#pragma unroll
  for (int mi = 0; mi < MI; ++mi) {
    int rowb = m0 + wr * (MI * 16) + mi * 16 + g * 4;
#pragma unroll
    for (int ni = 0; ni < 4; ++ni) {
      int col = n0 + wc * 64 + ni * 16 + c;
      float bv = bias[col];
#pragma unroll
      for (int r = 0; r < 4; ++r) {
        float v = (acc[mi][ni][r] + bv) * oscale;
        store_out(C, (size_t)(rowb + r) * N + col, v);
      }
    }
  }
}

// Fused QKV projection: 1D grid 768, XCD-chunked
__global__ __launch_bounds__(256) void gemm_qkv(const u16* __restrict__ xb,
                                                const u16* __restrict__ Wq, const u16* __restrict__ Wk,
                                                const u16* __restrict__ Wv,
                                                const float* __restrict__ bq, const float* __restrict__ bk,
                                                const float* __restrict__ bv,
                                                u16* __restrict__ Q, u16* __restrict__ Kb, u16* __restrict__ Vb,
                                                int M, int K, float qscale) {
  __shared__ u16 lsA[4096];
  __shared__ u16 lsB[4096];
  const int fid = blockIdx.x;
  const int xcd = fid & 7, i = fid >> 3;        // i in 0..95
  const int mloc = i / 24, nn = i % 24;
  const int m0 = (xcd * 4 + mloc) * 128;
  const int ng = nn * 128;
  const int sel = ng >> 10, n0 = ng & 1023;
  const u16*  W    = sel == 0 ? Wq : sel == 1 ? Wk : Wv;
  const float* bia = sel == 0 ? bq : sel == 1 ? bk : bv;
  u16*        Cp   = sel == 0 ? Q  : sel == 1 ? Kb : Vb;
  float os = sel == 0 ? qscale : 1.0f;
  gemm_core<4, u16>(xb, W, bia, Cp, M, 1024, K, os, m0, n0, lsA, lsB);
}

// Output projection: 1D grid 512, XCD-chunked, BM=64
__global__ __launch_bounds__(256) void gemm_wo(const u16* __restrict__ A, const u16* __restrict__ Bw,
                                               const float* __restrict__ bias, float* __restrict__ C,
                                               int M, int N, int K) {
  __shared__ u16 lsA[2048];
  __shared__ u16 lsB[4096];
  const int fid = blockIdx.x;
  const int xcd = fid & 7, i = fid >> 3;        // 0..63
  const int mloc = i >> 3, nn = i & 7;
  const int m0 = (xcd * 8 + mloc) * 64;
  const int n0 = nn * 128;
  gemm_core<2, float>(A, Bw, bias, C, M, N, K, 1.0f, m0, n0, lsA, lsB);
}

// ---------------- Flash attention, causal, 32x32 MFMA, in-register softmax.
// Grid 1024: block = 64 q-rows (qt), 4 waves: wave w -> q-subtile (w&1), kv parity (w>>1).
// Parities split kv tiles odd/even; merged at the end via f32 LDS.
// Q pre-scaled by log2(e)/8 -> exp2-domain softmax.
__device__ __forceinline__ void stage_k(const u16* __restrict__ Kg, size_t headoff, int kvb,
                                        int kRow0, int kColB, int w, u16* lsKbuf) {
#pragma unroll
  for (int r = 0; r < 2; ++r)
    gload_lds16((const char*)(Kg + headoff + (size_t)(kvb + r * 32 + kRow0) * H_) + kColB,
                (char*)lsKbuf + r * 4096 + w * 1024);
}

__device__ __forceinline__ void write_vt(u16* dst, const u32x2* va, const u32x2* vb,
                                         int vKv, int vD0, int vS) {
#pragma unroll
  for (int r = 0; r < 2; ++r) {
    int kvx = (r * 32 + vKv) ^ vS;
    u32 w0 = __builtin_amdgcn_perm(vb[r][0], va[r][0], 0x05040100u);
    u32 w1 = __builtin_amdgcn_perm(vb[r][0], va[r][0], 0x07060302u);
    u32 w2 = __builtin_amdgcn_perm(vb[r][1], va[r][1], 0x05040100u);
    u32 w3 = __builtin_amdgcn_perm(vb[r][1], va[r][1], 0x07060302u);
    *reinterpret_cast<u32*>(dst + (vD0 + 0) * 72 + kvx) = w0;
    *reinterpret_cast<u32*>(dst + (vD0 + 1) * 72 + kvx) = w1;
    *reinterpret_cast<u32*>(dst + (vD0 + 2) * 72 + kvx) = w2;
    *reinterpret_cast<u32*>(dst + (vD0 + 3) * 72 + kvx) = w3;
  }
}

// exp + row-sum + pack + cross-half exchange + PV for one 32-kv subtile (ktbase = 0 or 2)
__device__ __forceinline__ void pv_sub(const f32x16& sc, float mrun, int ktbase,
                                       const char* vtb, int hi, int c5,
                                       f32x16& o0, f32x16& o1, float& rs) {
  float p[16];
#pragma unroll
  for (int r = 0; r < 16; ++r) p[r] = ex2(sc[r] - mrun);
  rs += ((p[0] + p[1]) + (p[2] + p[3])) + ((p[4] + p[5]) + (p[6] + p[7]))
      + ((p[8] + p[9]) + (p[10] + p[11])) + ((p[12] + p[13]) + (p[14] + p[15]));
  u32 wd[4][2];
#pragma unroll
  for (int a = 0; a < 4; ++a) {
    wd[a][0] = cvtpk(p[4 * a + 0], p[4 * a + 1]);
    wd[a][1] = cvtpk(p[4 * a + 2], p[4 * a + 3]);
  }
#pragma unroll
  for (int ktp = 0; ktp < 2; ++ktp) {
    u32 mw[4];
#pragma unroll
    for (int u = 0; u < 2; ++u) {
      u32 A  = wd[2 * ktp][u], Bv = wd[2 * ktp + 1][u];
      u32 oA = (u32)__shfl_xor((int)A, 32);
      u32 oB = (u32)__shfl_xor((int)Bv, 32);
      mw[u]     = hi ? oB : A;   // kv pair (16kt+8hi+2u, +1)
      mw[2 + u] = hi ? Bv : oA;  // kv pair (16kt+8hi+4+2u, +1)
    }
    u32x4 pw = {mw[0], mw[1], mw[2], mw[3]};
    bf16x8 pb = __builtin_bit_cast(bf16x8, pw);
    const int kt = ktbase + ktp;
#pragma unroll
    for (int dt = 0; dt < 2; ++dt) {
      int d = 32 * dt + c5;
      int col = (kt * 32 + hi * 16) ^ (16 * ((d >> 3) & 7));   // bytes
      bf16x8 av = *reinterpret_cast<const bf16x8*>(vtb + d * 144 + col);
      f32x16& oo = dt ? o1 : o0;
      oo = __builtin_amdgcn_mfma_f32_32x32x16_bf16(av, pb, oo, 0, 0, 0);
    }
  }
}

__global__ __launch_bounds__(256, 4) void attn_fwd(const u16* __restrict__ Qg,
                                                   const u16* __restrict__ Kg,
                                                   const u16* __restrict__ Vg,
                                                   u16* __restrict__ Og) {
  __shared__ __align__(16) char smem[34816];
  u16* lsK  = (u16*)smem;                 // [2 tiles][64][64], XOR-swizzled rows
  u16* lsVt = (u16*)(smem + 16384);       // [2 tiles][64 d][72], col = kv ^ 8*((d>>3)&7)
  // epilogue overlays (after final barrier):
  float* lsO  = (float*)smem;             // [sub][dt][lane]*20 f32 stride
  float* lsML = (float*)(smem + 20480);   // [sub][{m,l}][32]
  u16*   lsOT = (u16*)(smem + 21504);     // [sub][32 q][72]

  const int blk = blockIdx.x;
  const int xcd = blk & 7, i = blk >> 3;
  const int qt  = 31 - (i >> 2);          // heavy q-tiles dispatch first
  const int bh  = xcd * 4 + (i & 3);      // 4 whole heads per XCD
  const int h = bh & 15, b = bh >> 4;

  const int t = threadIdx.x, w = t >> 6, lane = t & 63;
  const int sub = w & 1, par = w >> 1;
  const int c5 = lane & 31, hi = lane >> 5;
  const size_t headoff = (size_t)b * (S_ * H_) + (size_t)h * HD_;
  const int q0w = qt * 64 + 32 * sub;

  // K staging map: linear LDS dest, inverse-swizzled global source
  const int kO    = w * 1024 + lane * 16;
  const int kRow0 = kO >> 7;
  const int kColB = (kO & 127) ^ ((kRow0 & 7) << 4);
  // V staging map
  const int vKv = 2 * (t >> 4);
  const int vD0 = 4 * (t & 15);
  const int vS  = 8 * ((vD0 >> 3) & 7);

  // Q B-frags: B[k=d][j=q], lane: q=c5, d = 16kt + 8hi + j
  bf16x8 aq[4];
#pragma unroll
  for (int kt = 0; kt < 4; ++kt)
    aq[kt] = *reinterpret_cast<const bf16x8*>(Qg + headoff + (size_t)(q0w + c5) * H_ + kt * 16 + hi * 8);

  f32x16 oacc0 = {}, oacc1 = {};
  float mrun = -1e30f, lrun = 0.f;

  const int NIT = (qt >> 1) + 1;
  for (int n = 0; n < NIT; ++n) {
    const int kvb0 = 2 * n * 64;
    const bool has1 = (2 * n + 1) <= qt;

    // ---- stage both parity tiles (all threads) ----
    u32x2 va0[2], vb0[2], va1[2], vb1[2];
#pragma unroll
    for (int r = 0; r < 2; ++r) {
      const u16* vp = Vg + headoff + (size_t)(kvb0 + r * 32 + vKv) * H_ + vD0;
      va0[r] = *reinterpret_cast<const u32x2*>(vp);
      vb0[r] = *reinterpret_cast<const u32x2*>(vp + H_);
    }
    if (has1) {
#pragma unroll
      for (int r = 0; r < 2; ++r) {
        const u16* vp = Vg + headoff + (size_t)(kvb0 + 64 + r * 32 + vKv) * H_ + vD0;
        va1[r] = *reinterpret_cast<const u32x2*>(vp);
        vb1[r] = *reinterpret_cast<const u32x2*>(vp + H_);
      }
    }
    stage_k(Kg, headoff, kvb0, kRow0, kColB, w, lsK);
    if (has1) stage_k(Kg, headoff, kvb0 + 64, kRow0, kColB, w, lsK + 4096);
    asm volatile("s_waitcnt vmcnt(0)" ::: "memory");
    write_vt(lsVt, va0, vb0, vKv, vD0, vS);
    if (has1) write_vt(lsVt + 4608, va1, vb1, vKv, vD0, vS);
    __syncthreads();

    // ---- compute own parity tile ----
    const int myt = 2 * n + par;
    if (myt <= qt) {
      const char* kb  = (const char*)lsK  + par * 8192;
      const char* vtb = (const char*)lsVt + par * 9216;
      const int nkv = (myt == qt && sub == 0) ? 1 : 2;

      f32x16 sc0 = {}, sc1 = {};
      __builtin_amdgcn_s_setprio(1);
#pragma unroll
      for (int kt = 0; kt < 4; ++kt) {
        int colx = (kt * 32 + hi * 16) ^ ((c5 & 7) << 4);
        bf16x8 ak0 = *reinterpret_cast<const bf16x8*>(kb + c5 * 128 + colx);
        sc0 = __builtin_amdgcn_mfma_f32_32x32x16_bf16(ak0, aq[kt], sc0, 0, 0, 0);
      }
      if (nkv == 2) {
#pragma unroll
        for (int kt = 0; kt < 4; ++kt) {
          int colx = (kt * 32 + hi * 16) ^ ((c5 & 7) << 4);
          bf16x8 ak1 = *reinterpret_cast<const bf16x8*>(kb + (32 + c5) * 128 + colx);
          sc1 = __builtin_amdgcn_mfma_f32_32x32x16_bf16(ak1, aq[kt], sc1, 0, 0, 0);
        }
      }
      __builtin_amdgcn_s_setprio(0);

      // causal mask (diag tile only); score row kv = (r&3)+8*(r>>2)+4hi, col q = c5
      if (myt == qt) {
        const int qg = q0w + c5;
#pragma unroll
        for (int r = 0; r < 16; ++r) {
          int kvg = myt * 64 + (r & 3) + 8 * (r >> 2) + 4 * hi;
          sc0[r] = (kvg > qg) ? -1e30f : sc0[r];
          if (nkv == 2) sc1[r] = (kvg + 32 > qg) ? -1e30f : sc1[r];
        }
      }

      // column max: in-lane tree + one cross-half shfl
      float pm = sc0[0];
#pragma unroll
      for (int r = 1; r < 16; ++r) pm = fmaxf(pm, sc0[r]);
      if (nkv == 2) {
#pragma unroll
        for (int r = 0; r < 16; ++r) pm = fmaxf(pm, sc1[r]);
      }
      pm = fmaxf(pm, (float)__shfl_xor(pm, 32));

      // defer-max: rescale only when max grew by > 8 (exp2 domain)
      if (!__all(pm <= mrun + 8.0f)) {
        float mn = fmaxf(mrun, pm);
        float s8 = ex2(mrun - mn);
        mrun = mn; lrun *= s8;
#pragma unroll
        for (int r = 0; r < 16; ++r) { oacc0[r] *= s8; oacc1[r] *= s8; }
      }

      float rs = 0.f;
      pv_sub(sc0, mrun, 0, vtb, hi, c5, oacc0, oacc1, rs);
      if (nkv == 2) pv_sub(sc1, mrun, 2, vtb, hi, c5, oacc0, oacc1, rs);
      rs += (float)__shfl_xor(rs, 32);
      lrun += rs;
    }
    __syncthreads();
  }

  // ---- parity merge + output ----
  if (par == 0) {
    if (hi == 0) { lsML[sub * 64 + c5] = mrun; lsML[sub * 64 + 32 + c5] = lrun; }
#pragma unroll
    for (int dt = 0; dt < 2; ++dt) {
      float* dst = lsO + ((size_t)((sub * 2 + dt) * 64 + lane)) * 20;
      const f32x16& oo = dt ? oacc1 : oacc0;
#pragma unroll
      for (int k4 = 0; k4 < 4; ++k4) {
        f32x4 v4 = {oo[4 * k4], oo[4 * k4 + 1], oo[4 * k4 + 2], oo[4 * k4 + 3]};
        *reinterpret_cast<f32x4*>(dst + 4 * k4) = v4;
      }
    }
  }
  __syncthreads();
  if (par == 1) {
    float mA = lsML[sub * 64 + c5];
    float lA = lsML[sub * 64 + 32 + c5];
    float mn = fmaxf(mA, mrun);
    float sA = ex2(mA - mn), sB = ex2(mrun - mn);
    float linv = 1.0f / (lA * sA + lrun * sB);
    sA *= linv; sB *= linv;
    u16* ot = lsOT + sub * 32 * 72;
#pragma unroll
    for (int dt = 0; dt < 2; ++dt) {
      const float* sp = lsO + ((size_t)((sub * 2 + dt) * 64 + lane)) * 20;
      f32x4 a4[4];
#pragma unroll
      for (int k4 = 0; k4 < 4; ++k4) a4[k4] = *reinterpret_cast<const f32x4*>(sp + 4 * k4);
      const f32x16& oo = dt ? oacc1 : oacc0;
#pragma unroll
      for (int a = 0; a < 4; ++a)
#pragma unroll
        for (int u = 0; u < 2; ++u) {
          int r = 4 * a + 2 * u;
          float o0 = a4[a][2 * u]     * sA + oo[r]     * sB;
          float o1 = a4[a][2 * u + 1] * sA + oo[r + 1] * sB;
          int d = 32 * dt + 8 * a + 4 * hi + 2 * u;
          *reinterpret_cast<u32*>(ot + c5 * 72 + d) = cvtpk(o0, o1);
        }
    }
    asm volatile("s_waitcnt lgkmcnt(0)" ::: "memory");
    __builtin_amdgcn_sched_barrier(0);
#pragma unroll
    for (int rr = 0; rr < 4; ++rr) {
      int q = 8 * rr + (lane >> 3);
      int d8 = (lane & 7) * 8;
      u32x4 vv = *reinterpret_cast<const u32x4*>(ot + q * 72 + d8);
      *reinterpret_cast<u32x4*>(Og + headoff + (size_t)(qt * 64 + 32 * sub + q) * H_ + d8) = vv;
    }
  }
}

extern "C" void kernel_launch(void* const* d_in, const int* in_sizes, int n_in,
                              void* d_out, int out_size, void* d_ws, size_t ws_size,
                              hipStream_t stream) {
  const float* x  = (const float*)d_in[0];
  const float* Wq = (const float*)d_in[1];
  const float* bq = (const float*)d_in[2];
  const float* Wk = (const float*)d_in[3];
  const float* bk = (const float*)d_in[4];
  const float* Wv = (const float*)d_in[5];
  const float* bv = (const float*)d_in[6];
  const float* Wo = (const float*)d_in[7];
  const float* bo = (const float*)d_in[8];
  float* out = (float*)d_out;

  const size_t MT = (size_t)B_ * S_;            // 4096
  char* p = (char*)d_ws;
  u16* xb  = (u16*)p; p += MT * H_ * 2;         // reused as ctx buffer after QKV
  u16* Wqb = (u16*)p; p += (size_t)H_ * H_ * 2;
  u16* Wkb = (u16*)p; p += (size_t)H_ * H_ * 2;
  u16* Wvb = (u16*)p; p += (size_t)H_ * H_ * 2;
  u16* Wob = (u16*)p; p += (size_t)H_ * H_ * 2;
  u16* Qb  = (u16*)p; p += MT * H_ * 2;
  u16* Kb  = (u16*)p; p += MT * H_ * 2;
  u16* Vb  = (u16*)p; p += MT * H_ * 2;
  u16* Cb  = xb;

  cvt_all<<<8192, 256, 0, stream>>>(x, Wq, Wk, Wv, Wo, xb, Wqb, Wkb, Wvb, Wob);

  const float qscale = 0.125f * 1.44269504088896f;  // log2(e)/sqrt(HD)
  gemm_qkv<<<768, 256, 0, stream>>>(xb, Wqb, Wkb, Wvb, bq, bk, bv,
                                    Qb, Kb, Vb, (int)MT, H_, qscale);

  attn_fwd<<<1024, 256, 0, stream>>>(Qb, Kb, Vb, Cb);

  gemm_wo<<<512, 256, 0, stream>>>(Cb, Wob, bo, out, (int)MT, H_, H_);
}